// Round 5
// baseline (103.488 us; speedup 1.0000x reference)
//
#include <hip/hip_runtime.h>
#include <stdint.h>

#define CI 512
#define CO 512
#define HI 64
#define WI 64
#define HY 65
#define NB 8

typedef __bf16 bf16x8 __attribute__((ext_vector_type(8)));
typedef float f32x4 __attribute__((ext_vector_type(4)));

__device__ __forceinline__ unsigned short f2bf(float f) {
  unsigned int u = __float_as_uint(f);
  return (unsigned short)((u + 0x7fffu + ((u >> 16) & 1u)) >> 16);
}

// async global->LDS, 16B per lane. LDS dest = wave-uniform base + lane*16.
__device__ __forceinline__ void async16(void* lds, const void* g) {
  __builtin_amdgcn_global_load_lds(
      (const __attribute__((address_space(1))) uint32_t*)g,
      (__attribute__((address_space(3))) uint32_t*)lds, 16, 0, 0);
}

// ---------------- Kernel A: FIR prefilter (LDS-tiled separable) ----------------
#define CT 32
#define RT 13

__global__ __launch_bounds__(256) void fir_kernel(const float* __restrict__ x,
                                                  unsigned short* __restrict__ yt) {
  __shared__ float raw[CT][WI + 1];
  __shared__ float hrow[4][HY][CT];

  const int tid = threadIdx.x;
  const int bid = blockIdx.x;
  const int n = bid / 80;
  const int rem = bid % 80;
  const int c0 = (rem / 5) * CT;
  const int r0 = (rem % 5) * RT;

  const float* xb = x + ((size_t)n * CI + c0) * (HI * WI);

  const int lc = tid >> 3;
  const int lq = tid & 7;
  const int c = tid & (CT - 1);
  const int sb = tid >> 5;

  auto stage = [&](int hr) {
    __syncthreads();
    if ((unsigned)hr < (unsigned)HI) {
      const float* rowp = xb + ((size_t)lc * HI + hr) * WI;
      float4 a = *(const float4*)&rowp[lq * 4];
      float4 b = *(const float4*)&rowp[(lq + 8) * 4];
      raw[lc][lq * 4 + 0] = a.x; raw[lc][lq * 4 + 1] = a.y;
      raw[lc][lq * 4 + 2] = a.z; raw[lc][lq * 4 + 3] = a.w;
      raw[lc][(lq + 8) * 4 + 0] = b.x; raw[lc][(lq + 8) * 4 + 1] = b.y;
      raw[lc][(lq + 8) * 4 + 2] = b.z; raw[lc][(lq + 8) * 4 + 3] = b.w;
    }
    __syncthreads();
    const int slot = hr & 3;
    if ((unsigned)hr < (unsigned)HI) {
#pragma unroll
      for (int k = 0; k < 9; k++) {
        const int s = sb + (k << 3);
        if (s < HY) {
          float v = 0.f;
          if (s >= 2) v += raw[c][s - 2];
          if (s >= 1) v += 3.f * raw[c][s - 1];
          if (s <= 63) v += 3.f * raw[c][s];
          if (s <= 62) v += raw[c][s + 1];
          hrow[slot][s][c] = v;
        }
      }
    } else {
#pragma unroll
      for (int k = 0; k < 9; k++) {
        const int s = sb + (k << 3);
        if (s < HY) hrow[slot][s][c] = 0.f;
      }
    }
  };

  stage(r0 - 2);
  stage(r0 - 1);
  stage(r0);

  for (int i = 0; i < RT; i++) {
    const int r = r0 + i;
    stage(r + 1);
    __syncthreads();
    const int q0 = (r - 2) & 3, q1 = (r - 1) & 3, q2 = r & 3, q3 = (r + 1) & 3;
    unsigned short* yo = yt + (((size_t)n * HY + r) * HY) * CI + c0 + c;
#pragma unroll
    for (int k = 0; k < 9; k++) {
      const int s = sb + (k << 3);
      if (s < HY) {
        const float y = (hrow[q0][s][c] + 3.f * hrow[q1][s][c] +
                         3.f * hrow[q2][s][c] + hrow[q3][s][c]) * (1.f / 64.f);
        yo[(size_t)s * CI] = f2bf(y);
      }
    }
  }
}

// ---------------- Kernel B: weight transform ----------------
__global__ __launch_bounds__(256) void wt_kernel(const float* __restrict__ w,
                                                 unsigned short* __restrict__ wtb) {
  const int gid = blockIdx.x * 256 + threadIdx.x;
  const int ci = gid & (CI - 1);
  const int co = gid >> 9;
  const float* src = w + ((size_t)co * CI + ci) * 9;
#pragma unroll
  for (int t = 0; t < 9; t++) {
    wtb[((size_t)t * CO + co) * CI + ci] = f2bf(src[t]);
  }
}

// ---------------- Kernel B2: out = bias (pre-init for split-K atomics) ----------
__global__ __launch_bounds__(256) void init_kernel(const float* __restrict__ bias,
                                                   float* __restrict__ out) {
  const int gid = blockIdx.x * 256 + threadIdx.x;    // float4 id, 1048576 total
  const float bv = bias[(gid >> 8) & 511];
  float4 v = {bv, bv, bv, bv};
  *(float4*)(out + (size_t)gid * 4) = v;
}

// ---------------- Kernel C: implicit-GEMM conv, split-K=2 ----------------
// Tile: 128 co x 256 pos, BK=64, 36 k-steps per split (72 total = 9 taps x 8).
// 512 threads = 8 waves (2 co x 4 pos), wave tile 64x64, acc 4x4 f32x4.
// 3-buffer LDS (144 KB, 1 block/CU), depth-2 prefetch via global_load_lds,
// counted s_waitcnt vmcnt(6), raw s_barrier, XOR slot swizzle both sides.
// Loop unrolled x3 so buffer indices are compile-time (round-4 lesson).
// Epilogue: f32 atomicAdd into bias-initialized out (2 adds/element).
__global__ __launch_bounds__(512, 2) void conv_kernel(
    const unsigned short* __restrict__ wtb,
    const unsigned short* __restrict__ yt,
    float* __restrict__ out) {
  __shared__ unsigned short Alds[3][128 * 64];   // 3 x 16 KB
  __shared__ unsigned short Blds[3][256 * 64];   // 3 x 32 KB

  const int tid = threadIdx.x;
  // XCD-swizzled decode: 8 blocks sharing a pos-tile (4 co x 2 split) -> one XCD
  const int xcd = blockIdx.x & 7;
  const int j = blockIdx.x >> 3;                 // 0..31
  const int pos_tile = xcd * 4 + (j >> 3);       // 0..31
  const int variant = j & 7;
  const int co_t = (variant >> 1) << 7;          // 0,128,256,384
  const int split = variant & 1;
  const int ks0 = split * 36;
  const int m0 = pos_tile << 8;                  // 256 pos per tile
  const int n = m0 >> 10;                        // image index (uniform)

  // ---- staging per-lane global offsets (swizzled source) ----
  uint32_t aoff[2];
#pragma unroll
  for (int i = 0; i < 2; i++) {
    const int ch = tid + i * 512;                // A chunk 0..1023
    const int row = ch >> 3, s = ch & 7;
    aoff[i] = (uint32_t)((co_t + row) * CI + ((s ^ (row & 7)) << 3));
  }
  uint32_t boff[4];
#pragma unroll
  for (int i = 0; i < 4; i++) {
    const int ch = tid + i * 512;                // B chunk 0..2047
    const int p = ch >> 3, s = ch & 7;
    const int pos = m0 + p;
    const int ho = (pos & 1023) >> 5, wo = pos & 31;
    boff[i] = (uint32_t)(((n * HY + 2 * ho) * HY + 2 * wo) * CI + ((s ^ (p & 7)) << 3));
  }

  auto stg = [&](unsigned short* Ab, unsigned short* Bb, int gks) {
    const int tap = gks >> 3;
    const int ci0 = (gks & 7) << 6;
    const int kh = tap / 3, kw = tap - kh * 3;
    const unsigned short* wsrc = wtb + (size_t)tap * (CO * CI) + ci0;
    const unsigned short* ysrc = yt + (size_t)(kh * HY + kw) * CI + ci0;
#pragma unroll
    for (int i = 0; i < 2; i++)
      async16(Ab + (size_t)(tid + i * 512) * 8, wsrc + aoff[i]);
#pragma unroll
    for (int i = 0; i < 4; i++)
      async16(Bb + (size_t)(tid + i * 512) * 8, ysrc + boff[i]);
  };

  // ---- compute-side fragment offsets (swizzled read) ----
  const int wv = tid >> 6;
  const int wcoW = (wv >> 2) << 6;   // 0 / 64
  const int wposW = (wv & 3) << 6;   // 0 / 64 / 128 / 192
  const int l = tid & 63;
  const int ll = l & 15, kg = l >> 4;
  const int a7 = ll & 7;

  int aidx[4][2], bidx[4][2];
#pragma unroll
  for (int m = 0; m < 4; m++)
#pragma unroll
    for (int kk = 0; kk < 2; kk++)
      aidx[m][kk] = (wcoW + m * 16 + ll) * 64 + ((((kk << 2) | kg) ^ a7) << 3);
#pragma unroll
  for (int nf = 0; nf < 4; nf++)
#pragma unroll
    for (int kk = 0; kk < 2; kk++)
      bidx[nf][kk] = (wposW + nf * 16 + ll) * 64 + ((((kk << 2) | kg) ^ a7) << 3);

  f32x4 acc[4][4] = {};

  stg(&Alds[0][0], &Blds[0][0], ks0);
  stg(&Alds[1][0], &Blds[1][0], ks0 + 1);
  asm volatile("s_waitcnt vmcnt(6)" ::: "memory");   // own stage(0) landed
  __builtin_amdgcn_s_barrier();

#define COMPUTE(CUR)                                                        \
  {                                                                         \
    const unsigned short* Ac = &Alds[CUR][0];                               \
    const unsigned short* Bc = &Blds[CUR][0];                               \
    _Pragma("unroll") for (int kk = 0; kk < 2; kk++) {                      \
      const bf16x8 a0 = *(const bf16x8*)(Ac + aidx[0][kk]);                 \
      const bf16x8 a1 = *(const bf16x8*)(Ac + aidx[1][kk]);                 \
      const bf16x8 a2 = *(const bf16x8*)(Ac + aidx[2][kk]);                 \
      const bf16x8 a3 = *(const bf16x8*)(Ac + aidx[3][kk]);                 \
      const bf16x8 b0 = *(const bf16x8*)(Bc + bidx[0][kk]);                 \
      const bf16x8 b1 = *(const bf16x8*)(Bc + bidx[1][kk]);                 \
      const bf16x8 b2 = *(const bf16x8*)(Bc + bidx[2][kk]);                 \
      const bf16x8 b3 = *(const bf16x8*)(Bc + bidx[3][kk]);                 \
      __builtin_amdgcn_s_setprio(1);                                        \
      _Pragma("unroll") for (int m = 0; m < 4; m++) {                       \
        const bf16x8 am = (m == 0) ? a0 : (m == 1) ? a1 : (m == 2) ? a2 : a3; \
        acc[m][0] = __builtin_amdgcn_mfma_f32_16x16x32_bf16(am, b0, acc[m][0], 0, 0, 0); \
        acc[m][1] = __builtin_amdgcn_mfma_f32_16x16x32_bf16(am, b1, acc[m][1], 0, 0, 0); \
        acc[m][2] = __builtin_amdgcn_mfma_f32_16x16x32_bf16(am, b2, acc[m][2], 0, 0, 0); \
        acc[m][3] = __builtin_amdgcn_mfma_f32_16x16x32_bf16(am, b3, acc[m][3], 0, 0, 0); \
      }                                                                     \
      __builtin_amdgcn_s_setprio(0);                                        \
    }                                                                       \
  }

#define ITER(CUR, NXT, KSL)                                                 \
  {                                                                         \
    const int ksl = (KSL);                                                  \
    if (ksl + 2 < 36) stg(&Alds[NXT][0], &Blds[NXT][0], ks0 + ksl + 2);     \
    COMPUTE(CUR);                                                           \
    if (ksl < 34) {                                                         \
      asm volatile("s_waitcnt vmcnt(6)" ::: "memory");                      \
      __builtin_amdgcn_s_barrier();                                         \
    } else if (ksl == 34) {                                                 \
      asm volatile("s_waitcnt vmcnt(0)" ::: "memory");                      \
      __builtin_amdgcn_s_barrier();                                         \
    }                                                                       \
  }

  for (int kb = 0; kb < 36; kb += 3) {
    ITER(0, 2, kb);
    ITER(1, 0, kb + 1);
    ITER(2, 1, kb + 2);
  }
#undef ITER
#undef COMPUTE

  // Epilogue: C/D row=(lane>>4)*4+reg -> co; col=lane&15 -> pos (verified layout)
#pragma unroll
  for (int m = 0; m < 4; m++) {
#pragma unroll
    for (int r = 0; r < 4; r++) {
      const int co = co_t + wcoW + m * 16 + kg * 4 + r;
      float* orow = out + ((size_t)n * CO + co) * 1024;
#pragma unroll
      for (int nf = 0; nf < 4; nf++) {
        const int pos = m0 + wposW + nf * 16 + ll;
        atomicAdd(orow + (pos & 1023), acc[m][nf][r]);
      }
    }
  }
}

extern "C" void kernel_launch(void* const* d_in, const int* in_sizes, int n_in,
                              void* d_out, int out_size, void* d_ws, size_t ws_size,
                              hipStream_t stream) {
  const float* x = (const float*)d_in[0];     // [8,512,64,64]
  const float* w = (const float*)d_in[1];     // [512,512,3,3]
  const float* bias = (const float*)d_in[2];  // [512]
  float* out = (float*)d_out;                 // [8,512,32,32]

  unsigned short* yt = (unsigned short*)d_ws;                    // 8*65*65*512 bf16
  unsigned short* wtb = yt + (size_t)NB * HY * HY * CI;          // 9*512*512 bf16

  fir_kernel<<<NB * (CI / CT) * 5, 256, 0, stream>>>(x, yt);     // 640 blocks
  wt_kernel<<<(CO * CI) / 256, 256, 0, stream>>>(w, wtb);        // 1024 blocks
  init_kernel<<<4096, 256, 0, stream>>>(bias, out);              // out = bias
  conv_kernel<<<256, 512, 0, stream>>>(wtb, yt, out);            // 256 blocks, splitK=2
}